// Round 8
// baseline (694.691 us; speedup 1.0000x reference)
//
#include <hip/hip_runtime.h>

#define DEV __device__ __forceinline__

// DPP quad_perm broadcast (mov form): every lane of each 4-lane quad gets
// quad-lane Q (CTRL = 0x00 / 0x55 / 0xAA / 0xFF for Q = 0/1/2/3).
template<int CTRL>
DEV float dpp_qbcast(float x) {
  return __int_as_float(__builtin_amdgcn_update_dpp(
      0, __float_as_int(x), CTRL, 0xF, 0xF, true));
}

DEV float rd_lane(float x, int lane) {
  return __int_as_float(__builtin_amdgcn_readlane(__float_as_int(x), lane));
}

// T = 8192, H = 10, D = 1. One wave does the whole scan. Clock pinned
// ~1.2 GHz in this harness (R4/R5: DVFS never ramps; co-resident waves steal
// issue despite setprio) -> single wave, minimal serial chain is everything.
//
// Lane layout: lane = 4*k + g, g in {i,f,g,o}, k = hidden unit (lanes < 40).
// Rows prescaled by exponent constants (R2): sigmoid rows by -log2e, tanh
// row by -2log2e; cell state kept scaled C = -2log2e * c:
//   r       = rcp(1+exp2(gate'))   (i,f,o lanes: the sigmoid itself)
//   i*S*tanh(g) = fma(i*g_r, 2S, -S*i)          [t1, u, t2 below]
//   C_new   = f*C + i*S*tanh(g)                 [fmac with DPP f]
//   q       = rcp(1+exp2(C_new));  h = o*(2q-1) = fmac(-o, q<dpp>, 2o)
// DPP is FUSED into the consuming mul/fmac (v_*_dpp) -- no mov_dpp hop.
// C is valid only in lane 4k+2, h only in lane 4k+3: exactly what the
// readlane gather, the h-spill column (4m+3) and the projection consume.
// s_nop 1 guards the VALU-write -> DPP-read hazard (2 wait states).
//
// MODE: 0 = wide h-spill (ws >= 2 MiB), 1 = narrow h-spill (ws >= 320 KiB),
//       2 = in-loop projection (no ws).
template<int MODE>
__global__ __launch_bounds__(64, 1)
void lstm_seq_kernel(const float* __restrict__ X,
                     const float* __restrict__ W_ih,
                     const float* __restrict__ W_hh,
                     const float* __restrict__ b_ih,
                     const float* __restrict__ b_hh,
                     const float* __restrict__ W_lin,
                     const float* __restrict__ b_lin,
                     const float* __restrict__ h0,
                     const float* __restrict__ c0,
                     float* __restrict__ out,
                     float* __restrict__ hbuf) {
  const int lane = (int)threadIdx.x;      // 0..63
  __builtin_amdgcn_s_setprio(3);

  const int g = lane & 3;                 // gate index i,f,g,o
  const int k = lane >> 2;                // hidden unit 0..9 (lanes < 40)
  const bool active = (lane < 40);

  const float LOG2E = 1.4426950408889634f;
  const float S = -2.f * LOG2E;           // cell-state scale
  const float negS = -S;                  // +2log2e
  const float twoS = 2.f * S;             // -4log2e

  float wih = 0.f, bias = 0.f;
  float whh[10];
#pragma unroll
  for (int m = 0; m < 10; ++m) whh[m] = 0.f;
  if (active) {
    const int row = g * 10 + k;
    const float ce = (g == 2) ? S : -LOG2E;   // prescale constant
    wih  = W_ih[row] * ce;
    bias = (b_ih[row] + b_hh[row]) * ce;
#pragma unroll
    for (int m = 0; m < 10; ++m) whh[m] = W_hh[row * 10 + m] * ce;
  }

  float wl[10];
  float blin = 0.f;
  if (MODE == 2) {
#pragma unroll
    for (int m = 0; m < 10; ++m) wl[m] = W_lin[m];
    blin = b_lin[0];
  }

  float hs[10];
#pragma unroll
  for (int m = 0; m < 10; ++m) hs[m] = h0[m];
  float C = active ? c0[k] * S : 0.f;

  float xv = X[lane];                     // chunk 0 of X
  float outbuf = 0.f;
  const bool stlane = active && (g == 3); // o-lane owns h

  for (int chunk = 0; chunk < 128; ++chunk) {
    const int nb = (chunk + 1) * 64 + lane;
    const float xv_next = X[nb < 8192 ? nb : 8191];
    // Split bases so every unrolled store offset fits 13-bit signed imm.
    float* p0 = hbuf + chunk * 64 * 64 + 16 * 64 + lane;  // s in [0,31]
    float* p1 = hbuf + chunk * 64 * 64 + 48 * 64 + lane;  // s in [32,63]
    float* hp = hbuf + chunk * 64 * 10 + k;               // MODE 1 layout

#pragma unroll
    for (int s = 0; s < 64; ++s) {
      const float x_t = rd_lane(xv, s);   // constant lane index (full unroll)
      const float xb = __builtin_fmaf(x_t, wih, bias);  // off-chain head

      // gate' = xb + sum_m hs[m]*whh'[m]; 5 chains of depth 2 + add tree.
      float d0 = __builtin_fmaf(hs[0], whh[0], xb);
      float d1 = hs[2] * whh[2];
      float d2 = hs[4] * whh[4];
      float d3 = hs[6] * whh[6];
      float d4 = hs[8] * whh[8];
      d0 = __builtin_fmaf(hs[1], whh[1], d0);
      d1 = __builtin_fmaf(hs[3], whh[3], d1);
      d2 = __builtin_fmaf(hs[5], whh[5], d2);
      d3 = __builtin_fmaf(hs[7], whh[7], d3);
      d4 = __builtin_fmaf(hs[9], whh[9], d4);
      const float gate = ((d0 + d1) + (d2 + d3)) + d4;

      // Raw logistic; i,f,o lanes: sigmoid. g lane: tanh = 2r-1 (folded).
      const float r =
          __builtin_amdgcn_rcpf(1.f + __builtin_amdgcn_exp2f(gate));
      const float twor = r + r;                                  // off-chain
      float negr = __int_as_float(__float_as_int(r) ^ 0x80000000); // -r

      float h;
      if (MODE == 0) {
        // Fused-DPP quad combine. After this block Cn = C_new (lane 4k+2).
        float t1, u, Cn;
        asm("s_nop 1\n\t"                 // VALU(r) -> DPP(r) hazard guard
            "v_mul_f32_dpp %0, %3, %3 quad_perm:[0,0,0,0] row_mask:0xf bank_mask:0xf\n\t"
            "v_mul_f32_dpp %1, %3, %4 quad_perm:[0,0,0,0] row_mask:0xf bank_mask:0xf\n\t"
            "v_fma_f32 %2, %0, %5, %1\n\t"
            "v_fmac_f32_dpp %2, %3, %6 quad_perm:[1,1,1,1] row_mask:0xf bank_mask:0xf"
            : "=&v"(t1), "=&v"(u), "=&v"(Cn)
            : "v"(r), "v"(negS), "v"(twoS), "v"(C));
        C = Cn;
        const float q =
            __builtin_amdgcn_rcpf(1.f + __builtin_amdgcn_exp2f(C));
        // h = -r + q*(2r), q pulled from lane 4k+2 via fused DPP.
        asm("s_nop 1\n\t"                 // VALU(q) -> DPP(q) hazard guard
            "v_fmac_f32_dpp %0, %1, %2 quad_perm:[2,2,2,2] row_mask:0xf bank_mask:0xf"
            : "+v"(negr)
            : "v"(q), "v"(twor));
        h = negr;                          // valid in o-lane (4k+3)
      } else {
        // Portable path (MODE 1/2): mov-DPP broadcasts as in R7.
        const float iv = dpp_qbcast<0x00>(r);
        const float fv = dpp_qbcast<0x55>(r);
        const float gv = dpp_qbcast<0xAA>(r);
        const float gsc = __builtin_fmaf(gv, twoS, negS);
        C = __builtin_fmaf(fv, C, iv * gsc);
        const float q =
            __builtin_amdgcn_rcpf(1.f + __builtin_amdgcn_exp2f(C));
        h = __builtin_fmaf(q, twor, -r);
      }

      hs[0] = rd_lane(h, 3);  hs[1] = rd_lane(h, 7);
      hs[2] = rd_lane(h, 11); hs[3] = rd_lane(h, 15);
      hs[4] = rd_lane(h, 19); hs[5] = rd_lane(h, 23);
      hs[6] = rd_lane(h, 27); hs[7] = rd_lane(h, 31);
      hs[8] = rd_lane(h, 35); hs[9] = rd_lane(h, 39);

      if (MODE == 0) {
        // All-lane store; proj reads o-lane columns (4m+3).
        if (s < 32) p0[(s - 16) * 64] = h;
        else        p1[(s - 48) * 64] = h;
      } else if (MODE == 1) {
        if (stlane) hp[s * 10] = h;
      } else {
        float o0 = __builtin_fmaf(hs[0], wl[0], blin);
        float o1 = hs[1] * wl[1];
        float o2 = hs[2] * wl[2];
        o0 = __builtin_fmaf(hs[3], wl[3], o0);
        o1 = __builtin_fmaf(hs[4], wl[4], o1);
        o2 = __builtin_fmaf(hs[5], wl[5], o2);
        o0 = __builtin_fmaf(hs[6], wl[6], o0);
        o1 = __builtin_fmaf(hs[7], wl[7], o1);
        o2 = __builtin_fmaf(hs[8], wl[8], o2);
        o0 = __builtin_fmaf(hs[9], wl[9], o0);
        const float out_t = (o0 + o1) + o2;
        outbuf = (lane == s) ? out_t : outbuf;
      }
    }

    if (MODE == 2) out[chunk * 64 + lane] = outbuf;
    xv = xv_next;
  }
}

// Phase 2 (MODE 0): out[t] = b_lin + sum_m hbuf[t*64 + 4m+3] * W_lin[m]
__global__ __launch_bounds__(256)
void lstm_proj_wide(const float* __restrict__ hbuf,
                    const float* __restrict__ W_lin,
                    const float* __restrict__ b_lin,
                    float* __restrict__ out) {
  const int t = blockIdx.x * 256 + (int)threadIdx.x;
  float acc = b_lin[0];
  const float* hp = hbuf + t * 64;
#pragma unroll
  for (int m = 0; m < 10; ++m)
    acc = __builtin_fmaf(hp[m * 4 + 3], W_lin[m], acc);
  out[t] = acc;
}

// Phase 2 (MODE 1): out[t] = b_lin + sum_m hbuf[t*10 + m] * W_lin[m]
__global__ __launch_bounds__(256)
void lstm_proj_narrow(const float* __restrict__ hbuf,
                      const float* __restrict__ W_lin,
                      const float* __restrict__ b_lin,
                      float* __restrict__ out) {
  const int t = blockIdx.x * 256 + (int)threadIdx.x;
  float acc = b_lin[0];
  const float* hp = hbuf + t * 10;
#pragma unroll
  for (int m = 0; m < 10; ++m) acc = __builtin_fmaf(hp[m], W_lin[m], acc);
  out[t] = acc;
}

extern "C" void kernel_launch(void* const* d_in, const int* in_sizes, int n_in,
                              void* d_out, int out_size, void* d_ws, size_t ws_size,
                              hipStream_t stream) {
  const float* X     = (const float*)d_in[0];
  const float* W_ih  = (const float*)d_in[1];
  const float* W_hh  = (const float*)d_in[2];
  const float* b_ih  = (const float*)d_in[3];
  const float* b_hh  = (const float*)d_in[4];
  const float* W_lin = (const float*)d_in[5];
  const float* b_lin = (const float*)d_in[6];
  const float* h0    = (const float*)d_in[7];
  const float* c0    = (const float*)d_in[8];
  float* out = (float*)d_out;
  float* hbuf = (float*)d_ws;

  if (ws_size >= (size_t)8192 * 64 * sizeof(float)) {
    lstm_seq_kernel<0><<<1, 64, 0, stream>>>(X, W_ih, W_hh, b_ih, b_hh,
                                             W_lin, b_lin, h0, c0, out, hbuf);
    lstm_proj_wide<<<32, 256, 0, stream>>>(hbuf, W_lin, b_lin, out);
  } else if (ws_size >= (size_t)8192 * 10 * sizeof(float)) {
    lstm_seq_kernel<1><<<1, 64, 0, stream>>>(X, W_ih, W_hh, b_ih, b_hh,
                                             W_lin, b_lin, h0, c0, out, hbuf);
    lstm_proj_narrow<<<32, 256, 0, stream>>>(hbuf, W_lin, b_lin, out);
  } else {
    lstm_seq_kernel<2><<<1, 64, 0, stream>>>(X, W_ih, W_hh, b_ih, b_hh,
                                             W_lin, b_lin, h0, c0, out, hbuf);
  }
}

// Round 9
// 690.103 us; speedup vs baseline: 1.0066x; 1.0066x over previous
//
#include <hip/hip_runtime.h>

#define DEV __device__ __forceinline__

// DPP quad_perm broadcast (mov form): every lane of each 4-lane quad gets
// quad-lane Q (CTRL = 0x00 / 0x55 / 0xAA / 0xFF for Q = 0/1/2/3).
template<int CTRL>
DEV float dpp_qbcast(float x) {
  return __int_as_float(__builtin_amdgcn_update_dpp(
      0, __float_as_int(x), CTRL, 0xF, 0xF, true));
}

// Anti-CSE DPP broadcast: distinct dead 'old' argument makes each call
// unique (no CSE), so each result is single-use and the backend's
// GCNDPPCombine folds the mov_dpp into the consuming VOP2
// (v_mul_f32_dpp / v_fmac_f32_dpp). With bound_ctrl=1 and full masks the
// 'old' value is never read -> semantics identical.
template<int CTRL, int TAG>
DEV float dpp_qbcast_u(float x) {
  return __int_as_float(__builtin_amdgcn_update_dpp(
      TAG, __float_as_int(x), CTRL, 0xF, 0xF, true));
}

DEV float rd_lane(float x, int lane) {
  return __int_as_float(__builtin_amdgcn_readlane(__float_as_int(x), lane));
}

// T = 8192, H = 10, D = 1. One wave does the whole scan. Clock pinned
// ~1.2 GHz in this harness (R4/R5: DVFS never ramps; co-resident waves
// steal issue despite setprio) -> single wave, minimal serial chain wins.
//
// Lane layout: lane = 4*k + g, g in {i,f,g,o}, k = hidden unit (lanes < 40).
// Rows prescaled by exponent constants (R2): sigmoid rows by -log2e, tanh
// row by -2log2e; cell state kept scaled C = -2log2e * c:
//   r  = rcp(1+exp2(gate'))          (i,f,o lanes: the sigmoid itself)
//   t1 = i<dpp>*g_raw; t2 = fma(t1, 2S, i<dpp>*(-S)) = i*S*tanh(g)  [lane 4k+2]
//   C  = fmac(f<dpp>, C, t2)                                        [lane 4k+2]
//   q  = rcp(1+exp2(C)); h = fmac(q<dpp from 4k+2>, 2r, -r)         [lane 4k+3]
// All DPP reads are single-use (anti-CSE) so they fold into the consuming
// mul/fmac -- R8 proved the hand-asm version of this dataflow works but its
// s_nops/copies cost more than the fold saved; this is the portable form.
//
// MODE: 0 = wide h-spill (ws >= 2 MiB), 1 = narrow h-spill (ws >= 320 KiB),
//       2 = in-loop projection (no ws).
template<int MODE>
__global__ __launch_bounds__(64, 1)
void lstm_seq_kernel(const float* __restrict__ X,
                     const float* __restrict__ W_ih,
                     const float* __restrict__ W_hh,
                     const float* __restrict__ b_ih,
                     const float* __restrict__ b_hh,
                     const float* __restrict__ W_lin,
                     const float* __restrict__ b_lin,
                     const float* __restrict__ h0,
                     const float* __restrict__ c0,
                     float* __restrict__ out,
                     float* __restrict__ hbuf) {
  const int lane = (int)threadIdx.x;      // 0..63
  __builtin_amdgcn_s_setprio(3);

  const int g = lane & 3;                 // gate index i,f,g,o
  const int k = lane >> 2;                // hidden unit 0..9 (lanes < 40)
  const bool active = (lane < 40);

  const float LOG2E = 1.4426950408889634f;
  const float S = -2.f * LOG2E;           // cell-state scale
  const float negS = -S;                  // +2log2e
  const float twoS = 2.f * S;             // -4log2e

  float wih = 0.f, bias = 0.f;
  float whh[10];
#pragma unroll
  for (int m = 0; m < 10; ++m) whh[m] = 0.f;
  if (active) {
    const int row = g * 10 + k;
    const float ce = (g == 2) ? S : -LOG2E;   // prescale constant
    wih  = W_ih[row] * ce;
    bias = (b_ih[row] + b_hh[row]) * ce;
#pragma unroll
    for (int m = 0; m < 10; ++m) whh[m] = W_hh[row * 10 + m] * ce;
  }

  float wl[10];
  float blin = 0.f;
  if (MODE == 2) {
#pragma unroll
    for (int m = 0; m < 10; ++m) wl[m] = W_lin[m];
    blin = b_lin[0];
  }

  float hs[10];
#pragma unroll
  for (int m = 0; m < 10; ++m) hs[m] = h0[m];
  float C = active ? c0[k] * S : 0.f;

  float xv = X[lane];                     // chunk 0 of X
  float outbuf = 0.f;
  const bool stlane = active && (g == 3); // o-lane owns h

  for (int chunk = 0; chunk < 128; ++chunk) {
    const int nb = (chunk + 1) * 64 + lane;
    const float xv_next = X[nb < 8192 ? nb : 8191];
    // Split bases so every unrolled store offset fits 13-bit signed imm.
    float* p0 = hbuf + chunk * 64 * 64 + 16 * 64 + lane;  // s in [0,31]
    float* p1 = hbuf + chunk * 64 * 64 + 48 * 64 + lane;  // s in [32,63]
    float* hp = hbuf + chunk * 64 * 10 + k;               // MODE 1 layout

#pragma unroll
    for (int s = 0; s < 64; ++s) {
      const float x_t = rd_lane(xv, s);   // constant lane index (full unroll)
      const float xb = __builtin_fmaf(x_t, wih, bias);  // off-chain head

      // gate' = xb + sum_m hs[m]*whh'[m]; 5 chains of depth 2 + add tree.
      float d0 = __builtin_fmaf(hs[0], whh[0], xb);
      float d1 = hs[2] * whh[2];
      float d2 = hs[4] * whh[4];
      float d3 = hs[6] * whh[6];
      float d4 = hs[8] * whh[8];
      d0 = __builtin_fmaf(hs[1], whh[1], d0);
      d1 = __builtin_fmaf(hs[3], whh[3], d1);
      d2 = __builtin_fmaf(hs[5], whh[5], d2);
      d3 = __builtin_fmaf(hs[7], whh[7], d3);
      d4 = __builtin_fmaf(hs[9], whh[9], d4);
      const float gate = ((d0 + d1) + (d2 + d3)) + d4;

      // Raw logistic; i,f,o lanes: sigmoid. g lane: tanh = 2r-1 (folded).
      const float r =
          __builtin_amdgcn_rcpf(1.f + __builtin_amdgcn_exp2f(gate));
      const float twor = r + r;           // off-chain, feeds final h fmac

      float h;
      if (MODE == 0) {
        // Fused-DPP combine (portable). C_new valid in lane 4k+2 only.
        const float iv1 = dpp_qbcast_u<0x00, 0>(r);
        const float iv2 = dpp_qbcast_u<0x00, 1>(r);
        const float t1 = iv1 * r;               // lane 4k+2: i * g_raw
        const float u  = iv2 * negS;            // i * (-S)   (parallel)
        const float t2 = __builtin_fmaf(t1, twoS, u);  // i*S*tanh(g)
        const float fv1 = dpp_qbcast_u<0x55, 2>(r);
        C = __builtin_fmaf(fv1, C, t2);         // C_new, lane 4k+2
        const float q =
            __builtin_amdgcn_rcpf(1.f + __builtin_amdgcn_exp2f(C));
        const float qv = dpp_qbcast_u<0xAA, 3>(q);  // bcast from lane 4k+2
        h = -r;
        h = __builtin_fmaf(qv, twor, h);        // valid in o-lane (4k+3)
      } else {
        // Portable all-quad-lane path (MODE 1/2), as R7.
        const float iv = dpp_qbcast<0x00>(r);
        const float fv = dpp_qbcast<0x55>(r);
        const float gv = dpp_qbcast<0xAA>(r);
        const float gsc = __builtin_fmaf(gv, twoS, negS);
        C = __builtin_fmaf(fv, C, iv * gsc);
        const float q =
            __builtin_amdgcn_rcpf(1.f + __builtin_amdgcn_exp2f(C));
        h = __builtin_fmaf(q, twor, -r);
      }

      hs[0] = rd_lane(h, 3);  hs[1] = rd_lane(h, 7);
      hs[2] = rd_lane(h, 11); hs[3] = rd_lane(h, 15);
      hs[4] = rd_lane(h, 19); hs[5] = rd_lane(h, 23);
      hs[6] = rd_lane(h, 27); hs[7] = rd_lane(h, 31);
      hs[8] = rd_lane(h, 35); hs[9] = rd_lane(h, 39);

      if (MODE == 0) {
        // All-lane store; proj reads o-lane columns (4m+3).
        if (s < 32) p0[(s - 16) * 64] = h;
        else        p1[(s - 48) * 64] = h;
      } else if (MODE == 1) {
        if (stlane) hp[s * 10] = h;
      } else {
        float o0 = __builtin_fmaf(hs[0], wl[0], blin);
        float o1 = hs[1] * wl[1];
        float o2 = hs[2] * wl[2];
        o0 = __builtin_fmaf(hs[3], wl[3], o0);
        o1 = __builtin_fmaf(hs[4], wl[4], o1);
        o2 = __builtin_fmaf(hs[5], wl[5], o2);
        o0 = __builtin_fmaf(hs[6], wl[6], o0);
        o1 = __builtin_fmaf(hs[7], wl[7], o1);
        o2 = __builtin_fmaf(hs[8], wl[8], o2);
        o0 = __builtin_fmaf(hs[9], wl[9], o0);
        const float out_t = (o0 + o1) + o2;
        outbuf = (lane == s) ? out_t : outbuf;
      }
    }

    if (MODE == 2) out[chunk * 64 + lane] = outbuf;
    xv = xv_next;
  }
}

// Phase 2 (MODE 0): out[t] = b_lin + sum_m hbuf[t*64 + 4m+3] * W_lin[m]
__global__ __launch_bounds__(256)
void lstm_proj_wide(const float* __restrict__ hbuf,
                    const float* __restrict__ W_lin,
                    const float* __restrict__ b_lin,
                    float* __restrict__ out) {
  const int t = blockIdx.x * 256 + (int)threadIdx.x;
  float acc = b_lin[0];
  const float* hp = hbuf + t * 64;
#pragma unroll
  for (int m = 0; m < 10; ++m)
    acc = __builtin_fmaf(hp[m * 4 + 3], W_lin[m], acc);
  out[t] = acc;
}

// Phase 2 (MODE 1): out[t] = b_lin + sum_m hbuf[t*10 + m] * W_lin[m]
__global__ __launch_bounds__(256)
void lstm_proj_narrow(const float* __restrict__ hbuf,
                      const float* __restrict__ W_lin,
                      const float* __restrict__ b_lin,
                      float* __restrict__ out) {
  const int t = blockIdx.x * 256 + (int)threadIdx.x;
  float acc = b_lin[0];
  const float* hp = hbuf + t * 10;
#pragma unroll
  for (int m = 0; m < 10; ++m) acc = __builtin_fmaf(hp[m], W_lin[m], acc);
  out[t] = acc;
}

extern "C" void kernel_launch(void* const* d_in, const int* in_sizes, int n_in,
                              void* d_out, int out_size, void* d_ws, size_t ws_size,
                              hipStream_t stream) {
  const float* X     = (const float*)d_in[0];
  const float* W_ih  = (const float*)d_in[1];
  const float* W_hh  = (const float*)d_in[2];
  const float* b_ih  = (const float*)d_in[3];
  const float* b_hh  = (const float*)d_in[4];
  const float* W_lin = (const float*)d_in[5];
  const float* b_lin = (const float*)d_in[6];
  const float* h0    = (const float*)d_in[7];
  const float* c0    = (const float*)d_in[8];
  float* out = (float*)d_out;
  float* hbuf = (float*)d_ws;

  if (ws_size >= (size_t)8192 * 64 * sizeof(float)) {
    lstm_seq_kernel<0><<<1, 64, 0, stream>>>(X, W_ih, W_hh, b_ih, b_hh,
                                             W_lin, b_lin, h0, c0, out, hbuf);
    lstm_proj_wide<<<32, 256, 0, stream>>>(hbuf, W_lin, b_lin, out);
  } else if (ws_size >= (size_t)8192 * 10 * sizeof(float)) {
    lstm_seq_kernel<1><<<1, 64, 0, stream>>>(X, W_ih, W_hh, b_ih, b_hh,
                                             W_lin, b_lin, h0, c0, out, hbuf);
    lstm_proj_narrow<<<32, 256, 0, stream>>>(hbuf, W_lin, b_lin, out);
  } else {
    lstm_seq_kernel<2><<<1, 64, 0, stream>>>(X, W_ih, W_hh, b_ih, b_hh,
                                             W_lin, b_lin, h0, c0, out, hbuf);
  }
}

// Round 10
// 670.586 us; speedup vs baseline: 1.0359x; 1.0291x over previous
//
#include <hip/hip_runtime.h>

#define DEV __device__ __forceinline__

// DPP quad_perm broadcast: every lane of each 4-lane quad gets the value of
// quad-lane Q (CTRL = 0x00 / 0x55 / 0xAA / 0xFF for Q = 0/1/2/3).
template<int CTRL>
DEV float dpp_qbcast(float x) {
  return __int_as_float(__builtin_amdgcn_update_dpp(
      0, __float_as_int(x), CTRL, 0xF, 0xF, true));
}

DEV float rd_lane(float x, int lane) {
  return __int_as_float(__builtin_amdgcn_readlane(__float_as_int(x), lane));
}

// T = 8192, H = 10, D = 1. One wave does the whole scan. Clock is pinned at
// ~1.2 GHz for this harness (R4/R5 spinner experiments: DVFS never ramps,
// and co-resident waves steal issue slots despite setprio) -> single wave,
// minimal serial chain is optimal. R8/R9 proved DPP-fusion variants are
// neutral-to-negative: this (R7) form is the measured chain floor
// (~98 cy/step vs ~90 modeled minimum).
//
// Lane layout: lane = 4*k + g, g in {i,f,g,o}, k = hidden unit (lanes < 40).
// Rows prescaled by exponent constants (R2): sigmoid rows by -log2e, tanh
// row by -2log2e; cell state kept scaled C = -2log2e * c. So:
//   sigmoid = rcp(1+exp2(gate'))      (i,f,o lanes)
//   r_g     = rcp(1+exp2(gate'))      -> tanh = 2r-1 (folded into C update)
//   tanh(c) = 2q-1, q = rcp(1+exp2(C))
//   h       = r*(2q-1) = fma(q, 2r, -r)   (2r computed off-chain)
// h is computed locally in the o-lane (its r IS the o sigmoid); the next
// step's dot gathers h from lanes 4m+3 via readlane.
//
// MODE: 0 = wide h-spill (ws >= 2 MiB), 1 = narrow h-spill (ws >= 320 KiB),
//       2 = in-loop projection (no ws).
template<int MODE>
__global__ __launch_bounds__(64, 1)
void lstm_seq_kernel(const float* __restrict__ X,
                     const float* __restrict__ W_ih,
                     const float* __restrict__ W_hh,
                     const float* __restrict__ b_ih,
                     const float* __restrict__ b_hh,
                     const float* __restrict__ W_lin,
                     const float* __restrict__ b_lin,
                     const float* __restrict__ h0,
                     const float* __restrict__ c0,
                     float* __restrict__ out,
                     float* __restrict__ hbuf) {
  const int lane = (int)threadIdx.x;      // 0..63
  __builtin_amdgcn_s_setprio(3);

  const int g = lane & 3;                 // gate index i,f,g,o
  const int k = lane >> 2;                // hidden unit 0..9 (lanes < 40)
  const bool active = (lane < 40);

  const float LOG2E = 1.4426950408889634f;
  const float S = -2.f * LOG2E;           // cell-state scale

  float wih = 0.f, bias = 0.f;
  float whh[10];
#pragma unroll
  for (int m = 0; m < 10; ++m) whh[m] = 0.f;
  if (active) {
    const int row = g * 10 + k;
    const float ce = (g == 2) ? S : -LOG2E;   // prescale constant
    wih  = W_ih[row] * ce;
    bias = (b_ih[row] + b_hh[row]) * ce;
#pragma unroll
    for (int m = 0; m < 10; ++m) whh[m] = W_hh[row * 10 + m] * ce;
  }

  float wl[10];
  float blin = 0.f;
  if (MODE == 2) {
#pragma unroll
    for (int m = 0; m < 10; ++m) wl[m] = W_lin[m];
    blin = b_lin[0];
  }

  float hs[10];
#pragma unroll
  for (int m = 0; m < 10; ++m) hs[m] = h0[m];
  float C = active ? c0[k] * S : 0.f;

  float xv = X[lane];                     // chunk 0 of X
  float outbuf = 0.f;
  const bool stlane = active && (g == 3); // o-lane owns h

  for (int chunk = 0; chunk < 128; ++chunk) {
    const int nb = (chunk + 1) * 64 + lane;
    const float xv_next = X[nb < 8192 ? nb : 8191];
    // Split bases so every unrolled store offset fits 13-bit signed imm:
    // offsets (s-16)*256B and (s-48)*256B are in [-4096, 3840].
    float* p0 = hbuf + chunk * 64 * 64 + 16 * 64 + lane;  // s in [0,31]
    float* p1 = hbuf + chunk * 64 * 64 + 48 * 64 + lane;  // s in [32,63]
    float* hp = hbuf + chunk * 64 * 10 + k;               // MODE 1 layout

#pragma unroll
    for (int s = 0; s < 64; ++s) {
      const float x_t = rd_lane(xv, s);   // constant lane index (full unroll)
      const float xb = __builtin_fmaf(x_t, wih, bias);  // off-chain head

      // gate' = xb + sum_m hs[m]*whh'[m]; 5 chains of depth 2 + add tree.
      float d0 = __builtin_fmaf(hs[0], whh[0], xb);
      float d1 = hs[2] * whh[2];
      float d2 = hs[4] * whh[4];
      float d3 = hs[6] * whh[6];
      float d4 = hs[8] * whh[8];
      d0 = __builtin_fmaf(hs[1], whh[1], d0);
      d1 = __builtin_fmaf(hs[3], whh[3], d1);
      d2 = __builtin_fmaf(hs[5], whh[5], d2);
      d3 = __builtin_fmaf(hs[7], whh[7], d3);
      d4 = __builtin_fmaf(hs[9], whh[9], d4);
      const float gate = ((d0 + d1) + (d2 + d3)) + d4;

      // Raw logistic; i,f,o lanes: sigmoid. g lane: tanh = 2r-1 (folded).
      const float r =
          __builtin_amdgcn_rcpf(1.f + __builtin_amdgcn_exp2f(gate));
      const float twor = r + r;           // off-chain, feeds final h fma

      const float iv = dpp_qbcast<0x00>(r);
      const float fv = dpp_qbcast<0x55>(r);
      const float gv = dpp_qbcast<0xAA>(r);

      const float gsc = __builtin_fmaf(gv, 2.f * S, -S);  // S*tanh(gate_g)
      C = __builtin_fmaf(fv, C, iv * gsc);                // scaled cell state

      const float q =
          __builtin_amdgcn_rcpf(1.f + __builtin_amdgcn_exp2f(C));
      // h = r*(2q-1) = q*(2r) - r : one fma on the chain.
      const float h = __builtin_fmaf(q, twor, -r);  // valid in o-lane

      hs[0] = rd_lane(h, 3);  hs[1] = rd_lane(h, 7);
      hs[2] = rd_lane(h, 11); hs[3] = rd_lane(h, 15);
      hs[4] = rd_lane(h, 19); hs[5] = rd_lane(h, 23);
      hs[6] = rd_lane(h, 27); hs[7] = rd_lane(h, 31);
      hs[8] = rd_lane(h, 35); hs[9] = rd_lane(h, 39);

      if (MODE == 0) {
        // All-lane store; proj reads o-lane columns (4m+3).
        if (s < 32) p0[(s - 16) * 64] = h;
        else        p1[(s - 48) * 64] = h;
      } else if (MODE == 1) {
        if (stlane) hp[s * 10] = h;
      } else {
        float o0 = __builtin_fmaf(hs[0], wl[0], blin);
        float o1 = hs[1] * wl[1];
        float o2 = hs[2] * wl[2];
        o0 = __builtin_fmaf(hs[3], wl[3], o0);
        o1 = __builtin_fmaf(hs[4], wl[4], o1);
        o2 = __builtin_fmaf(hs[5], wl[5], o2);
        o0 = __builtin_fmaf(hs[6], wl[6], o0);
        o1 = __builtin_fmaf(hs[7], wl[7], o1);
        o2 = __builtin_fmaf(hs[8], wl[8], o2);
        o0 = __builtin_fmaf(hs[9], wl[9], o0);
        const float out_t = (o0 + o1) + o2;
        outbuf = (lane == s) ? out_t : outbuf;
      }
    }

    if (MODE == 2) out[chunk * 64 + lane] = outbuf;
    xv = xv_next;
  }
}

// Phase 2 (MODE 0): out[t] = b_lin + sum_m hbuf[t*64 + 4m+3] * W_lin[m]
__global__ __launch_bounds__(256)
void lstm_proj_wide(const float* __restrict__ hbuf,
                    const float* __restrict__ W_lin,
                    const float* __restrict__ b_lin,
                    float* __restrict__ out) {
  const int t = blockIdx.x * 256 + (int)threadIdx.x;
  float acc = b_lin[0];
  const float* hp = hbuf + t * 64;
#pragma unroll
  for (int m = 0; m < 10; ++m)
    acc = __builtin_fmaf(hp[m * 4 + 3], W_lin[m], acc);
  out[t] = acc;
}

// Phase 2 (MODE 1): out[t] = b_lin + sum_m hbuf[t*10 + m] * W_lin[m]
__global__ __launch_bounds__(256)
void lstm_proj_narrow(const float* __restrict__ hbuf,
                      const float* __restrict__ W_lin,
                      const float* __restrict__ b_lin,
                      float* __restrict__ out) {
  const int t = blockIdx.x * 256 + (int)threadIdx.x;
  float acc = b_lin[0];
  const float* hp = hbuf + t * 10;
#pragma unroll
  for (int m = 0; m < 10; ++m) acc = __builtin_fmaf(hp[m], W_lin[m], acc);
  out[t] = acc;
}

extern "C" void kernel_launch(void* const* d_in, const int* in_sizes, int n_in,
                              void* d_out, int out_size, void* d_ws, size_t ws_size,
                              hipStream_t stream) {
  const float* X     = (const float*)d_in[0];
  const float* W_ih  = (const float*)d_in[1];
  const float* W_hh  = (const float*)d_in[2];
  const float* b_ih  = (const float*)d_in[3];
  const float* b_hh  = (const float*)d_in[4];
  const float* W_lin = (const float*)d_in[5];
  const float* b_lin = (const float*)d_in[6];
  const float* h0    = (const float*)d_in[7];
  const float* c0    = (const float*)d_in[8];
  float* out = (float*)d_out;
  float* hbuf = (float*)d_ws;

  if (ws_size >= (size_t)8192 * 64 * sizeof(float)) {
    lstm_seq_kernel<0><<<1, 64, 0, stream>>>(X, W_ih, W_hh, b_ih, b_hh,
                                             W_lin, b_lin, h0, c0, out, hbuf);
    lstm_proj_wide<<<32, 256, 0, stream>>>(hbuf, W_lin, b_lin, out);
  } else if (ws_size >= (size_t)8192 * 10 * sizeof(float)) {
    lstm_seq_kernel<1><<<1, 64, 0, stream>>>(X, W_ih, W_hh, b_ih, b_hh,
                                             W_lin, b_lin, h0, c0, out, hbuf);
    lstm_proj_narrow<<<32, 256, 0, stream>>>(hbuf, W_lin, b_lin, out);
  } else {
    lstm_seq_kernel<2><<<1, 64, 0, stream>>>(X, W_ih, W_hh, b_ih, b_hh,
                                             W_lin, b_lin, h0, c0, out, hbuf);
  }
}